// Round 15
// baseline (51.486 us; speedup 1.0000x reference)
//
#include <hip/hip_runtime.h>
#include <hip/hip_bf16.h>
#include <stdint.h>

#define NROWS 8192
#define BROWS 4096
#define LN2 0.6931471805599453f
#define FSC 8.944507e-4f        // (1/T)*log2(e) / 127^2, T=0.1
#define NBLK 1088               // sum_{it=0}^{127} ceil((128-it)/8) = 8*136

typedef __attribute__((ext_vector_type(4))) int i32x4;

__device__ inline void gload_lds16(const void* g, void* l) {
  __builtin_amdgcn_global_load_lds((const __attribute__((address_space(1))) void*)g,
                                   (__attribute__((address_space(3))) void*)l,
                                   16, 0, 0);
}

// Kernel A: L2-normalize rows, quantize to i8 (q = rn(127*v/||v||)); zero denom/out.
__global__ __launch_bounds__(256) void knorm(const float* __restrict__ zi,
                                             const float* __restrict__ zj,
                                             int* __restrict__ reps,   // i8 packed, 64 ints/row
                                             float* __restrict__ denom,
                                             float* __restrict__ out) {
  int w = threadIdx.x >> 6, l = threadIdx.x & 63;
  int row = blockIdx.x * 4 + w;
  const float* src = (row < BROWS) ? (zi + (size_t)row * 256)
                                   : (zj + (size_t)(row - BROWS) * 256);
  float4 v = ((const float4*)src)[l];
  float ss = v.x * v.x + v.y * v.y + v.z * v.z + v.w * v.w;
#pragma unroll
  for (int m = 1; m < 64; m <<= 1) ss += __shfl_xor(ss, m, 64);
  float sc = 127.0f / fmaxf(sqrtf(ss), 1e-12f);
  int q0 = __float2int_rn(v.x * sc), q1 = __float2int_rn(v.y * sc);
  int q2 = __float2int_rn(v.z * sc), q3 = __float2int_rn(v.w * sc);
  reps[(size_t)row * 64 + l] =
      (q0 & 255) | ((q1 & 255) << 8) | ((q2 & 255) << 16) | ((q3 & 255) << 24);
  if (l == 0) denom[row] = 0.f;
  if (row == 0 && l == 0) out[0] = 0.f;
}

// Kernel B: BARRIER-FREE upper-tri sim, i8 MFMA 16x16x64. ONE WAVE PER BLOCK:
// block = 64-row strip x 512-col chunk; the wave owns a private dbuf of 8KB
// 32-col B-tiles staged via its own gload_lds and waits only its own vmcnt.
// No s_barrier anywhere. 4-bit XOR swizzle -> 2-way (free) LDS reads.
__global__ __launch_bounds__(64, 2) void ksim(const int* __restrict__ reps_,
                                              float* __restrict__ denom,
                                              float* __restrict__ pos) {
  __shared__ uint4 smem[2][512];     // 2 x 32 reps-rows x 256 B = 16 KB
  __shared__ float colacc[512];      // 2 KB (single wave: non-atomic adds ok)
  int l = threadIdx.x;               // 0..63
  int kgrp = l >> 4;

  // ---- XCD swizzle (1088 = 8*136, bijective) + block -> (strip it, chunk q) ----
  int b = blockIdx.x;
  int orig = (b & 7) * 136 + (b >> 3);
  int rem = orig, it = 0, ch;
  while (rem >= (ch = (128 - it + 7) >> 3)) { rem -= ch; ++it; }
  int q = rem;
  int rowbase = it * 64;
  int cs0 = rowbase + q * 512;
  int len = NROWS - cs0; if (len > 512) len = 512;
  int ntile = len >> 5;              // 2..16, always even

#pragma unroll
  for (int i = 0; i < 8; ++i) colacc[l + 64 * i] = 0.f;

  // ---- staging: 32 reps-rows x 256B -> 8KB buffer; linear LDS dest, 4-bit
  //      XOR pre-swizzled source (involution with the read-side XOR) ----
  auto stage = [&](int bufi, int colbase) {
#pragma unroll
    for (int i = 0; i < 8; ++i) {
      int lr = i * 4 + (l >> 4);     // local row 0..31
      int kb = ((l & 15) * 16) ^ ((lr & 15) << 4);
      gload_lds16((const char*)reps_ + (size_t)(colbase + lr) * 256 + kb,
                  (void*)&smem[bufi][i * 64]);
    }
  };
  stage(0, cs0);

  // ---- A fragments: 64-row strip; lane holds row rowbase+fr*16+(l&15),
  //      bytes [kk*64 + kgrp*16, +16) ----
  i32x4 a[4][4];
  {
    const uint4* r4 = (const uint4*)reps_;
    int arow = rowbase + (l & 15);
#pragma unroll
    for (int fr = 0; fr < 4; ++fr)
#pragma unroll
      for (int kk = 0; kk < 4; ++kk)
        a[fr][kk] = __builtin_bit_cast(i32x4,
            r4[(size_t)(arow + fr * 16) * 16 + kk * 4 + kgrp]);
  }

  float rowsum[4][4];
#pragma unroll
  for (int fr = 0; fr < 4; ++fr)
#pragma unroll
    for (int r = 0; r < 4; ++r) rowsum[fr][r] = 0.f;

  int r0 = rowbase + kgrp * 4;
  int buf = 0;

  for (int t = 0; t < ntile; ++t) {
    // issue next stage, then wait only THIS wave's older loads (stage(t) + A)
    if (t + 1 < ntile) {
      stage(buf ^ 1, cs0 + 32 * (t + 1));
      asm volatile("s_waitcnt vmcnt(8)" ::: "memory");
    } else {
      asm volatile("s_waitcnt vmcnt(0)" ::: "memory");
    }
    __builtin_amdgcn_sched_barrier(0);

    const char* bb = (const char*)&smem[0][0] + buf * 8192;
    i32x4 acc[4][2];
    const i32x4 zero = {0, 0, 0, 0};
    __builtin_amdgcn_s_setprio(1);
#pragma unroll
    for (int kk = 0; kk < 4; ++kk) {
      i32x4 bf[2];
#pragma unroll
      for (int fc = 0; fc < 2; ++fc) {
        int lr = (l & 15) + fc * 16;
        bf[fc] = *(const i32x4*)(bb + lr * 256 + ((((kk * 4 + kgrp) ^ (lr & 15))) << 4));
      }
#pragma unroll
      for (int fr = 0; fr < 4; ++fr)
#pragma unroll
        for (int fc = 0; fc < 2; ++fc) {
          if (kk == 0)
            acc[fr][fc] = __builtin_amdgcn_mfma_i32_16x16x64_i8(a[fr][0], bf[fc], zero, 0, 0, 0);
          else
            acc[fr][fc] = __builtin_amdgcn_mfma_i32_16x16x64_i8(a[fr][kk], bf[fc], acc[fr][fc], 0, 0, 0);
        }
    }
    __builtin_amdgcn_s_setprio(0);

    // ---- epilogue: s = I*FSC; e = exp2(s); diag mask; rowsum + col partials ----
    int cb = cs0 + 32 * t;
    bool docol = !(q == 0 && t < 2);        // diag 64-col window spans t=0,1
    bool dopos = (q == 8) && (t < 2) && (it < 64);
    float cp0 = 0.f, cp1 = 0.f;
    int cbase = cb + (l & 15);
#pragma unroll
    for (int fr = 0; fr < 4; ++fr)
#pragma unroll
      for (int fc = 0; fc < 2; ++fc)
#pragma unroll
        for (int r = 0; r < 4; ++r) {
          int rg = r0 + fr * 16 + r;
          int cg = cbase + fc * 16;
          float s = (float)acc[fr][fc][r] * FSC;
          float e = __builtin_amdgcn_exp2f(s);
          e = (rg == cg) ? 0.f : e;
          if (dopos && cg == rg + BROWS) pos[rg] = s;
          rowsum[fr][r] += e;
          if (fc == 0) cp0 += e; else cp1 += e;
        }
    if (docol) {
      cp0 += __shfl_xor(cp0, 16, 64); cp0 += __shfl_xor(cp0, 32, 64);
      cp1 += __shfl_xor(cp1, 16, 64); cp1 += __shfl_xor(cp1, 32, 64);
      if (l < 16) {                       // single wave: plain adds, no atomics
        int off = (cb - cs0) + l;
        colacc[off] += cp0;
        colacc[off + 16] += cp1;
      }
    }
    buf ^= 1;
  }

  // ---- row sums: reduce 16 col-lanes; 4 lanes issue global atomics ----
#pragma unroll
  for (int fr = 0; fr < 4; ++fr)
#pragma unroll
    for (int r = 0; r < 4; ++r) {
      float v = rowsum[fr][r];
      v += __shfl_xor(v, 1, 64);
      v += __shfl_xor(v, 2, 64);
      v += __shfl_xor(v, 4, 64);
      v += __shfl_xor(v, 8, 64);
      if ((l & 15) == 0) atomicAdd(&denom[r0 + fr * 16 + r], v);
    }

  // ---- col sums: flush colacc, one atomic per nonzero column ----
#pragma unroll
  for (int i = 0; i < 8; ++i) {
    int off = l + 64 * i;
    float v = colacc[off];
    int col = cs0 + off;
    if (col < NROWS && v != 0.f) atomicAdd(&denom[col], v);
  }
}

// Kernel F: + (1/N) * sum_i (log(denom_i) - pos_{i mod B} * ln2)   [pos in log2 units]
__global__ __launch_bounds__(256) void kfin(const float* __restrict__ denom,
                                            const float* __restrict__ pos,
                                            float* __restrict__ out) {
  int i = blockIdx.x * 256 + threadIdx.x;
  float v = (logf(denom[i]) - pos[i & 4095] * LN2) * (1.0f / 8192.0f);
#pragma unroll
  for (int m = 1; m < 64; m <<= 1) v += __shfl_xor(v, m, 64);
  __shared__ float part[4];
  if ((threadIdx.x & 63) == 0) part[threadIdx.x >> 6] = v;
  __syncthreads();
  if (threadIdx.x == 0)
    atomicAdd(out, part[0] + part[1] + part[2] + part[3]);
}

extern "C" void kernel_launch(void* const* d_in, const int* in_sizes, int n_in,
                              void* d_out, int out_size, void* d_ws, size_t ws_size,
                              hipStream_t stream) {
  (void)in_sizes; (void)n_in; (void)out_size; (void)ws_size;
  const float* zi = (const float*)d_in[0];
  const float* zj = (const float*)d_in[1];
  float* out = (float*)d_out;
  char* ws = (char*)d_ws;
  int* reps    = (int*)ws;                                    // 2 MB (i8 packed)
  float* denom = (float*)(ws + 2097152);                      // 32 KB
  float* pos   = (float*)(ws + 2097152 + 32768);              // 16 KB

  knorm<<<2048, 256, 0, stream>>>(zi, zj, reps, denom, out);
  ksim<<<NBLK, 64, 0, stream>>>(reps, denom, pos);
  kfin<<<32, 256, 0, stream>>>(denom, pos, out);
}

// Round 16
// 37.891 us; speedup vs baseline: 1.3588x; 1.3588x over previous
//
#include <hip/hip_runtime.h>
#include <hip/hip_bf16.h>
#include <stdint.h>

#define NROWS 8192
#define BROWS 4096
#define LN2 0.6931471805599453f
#define FSC 8.944507e-4f        // (1/T)*log2(e) / 127^2, T=0.1
#define KMAD 7503               // round(FSC * 2^23)
#define CBITS 1064989150        // (127 - 0.0434) * 2^23  (Schraudolph exp2)
#define NBLK 2112               // sum_{it=0}^{127} ceil((128-it)/4) = 8*264

typedef __attribute__((ext_vector_type(4))) int i32x4;

__device__ inline void gload_lds16(const void* g, void* l) {
  __builtin_amdgcn_global_load_lds((const __attribute__((address_space(1))) void*)g,
                                   (__attribute__((address_space(3))) void*)l,
                                   16, 0, 0);
}

// Kernel A: L2-normalize rows, quantize to i8; store qss=sum(q^2); zero denom/out.
__global__ __launch_bounds__(256) void knorm(const float* __restrict__ zi,
                                             const float* __restrict__ zj,
                                             int* __restrict__ reps,   // i8 packed
                                             int* __restrict__ qss,
                                             float* __restrict__ denom,
                                             float* __restrict__ out) {
  int w = threadIdx.x >> 6, l = threadIdx.x & 63;
  int row = blockIdx.x * 4 + w;
  const float* src = (row < BROWS) ? (zi + (size_t)row * 256)
                                   : (zj + (size_t)(row - BROWS) * 256);
  float4 v = ((const float4*)src)[l];
  float ss = v.x * v.x + v.y * v.y + v.z * v.z + v.w * v.w;
#pragma unroll
  for (int m = 1; m < 64; m <<= 1) ss += __shfl_xor(ss, m, 64);
  float sc = 127.0f / fmaxf(sqrtf(ss), 1e-12f);
  int q0 = __float2int_rn(v.x * sc), q1 = __float2int_rn(v.y * sc);
  int q2 = __float2int_rn(v.z * sc), q3 = __float2int_rn(v.w * sc);
  reps[(size_t)row * 64 + l] =
      (q0 & 255) | ((q1 & 255) << 8) | ((q2 & 255) << 16) | ((q3 & 255) << 24);
  int qs = q0 * q0 + q1 * q1 + q2 * q2 + q3 * q3;
#pragma unroll
  for (int m = 1; m < 64; m <<= 1) qs += __shfl_xor(qs, m, 64);
  if (l == 0) { denom[row] = 0.f; qss[row] = qs; }
  if (row == 0 && l == 0) out[0] = 0.f;
}

// Kernel B: barrier-free upper-tri sim, i8 MFMA 16x16x64, ONE WAVE PER BLOCK.
// Epilogue: e = schraudolph-exp2 via ONE v_mad_i32_i24 + bitcast (no mask,
// no mul, no v_exp). Diagonal included; subtracted exactly in kfin.
// Block = 64-row strip x 256-col chunk -> 2112 blocks (~8/CU, 2 waves/SIMD).
__global__ __launch_bounds__(64, 2) void ksim(const int* __restrict__ reps_,
                                              float* __restrict__ denom,
                                              float* __restrict__ pos) {
  __shared__ uint4 smem[2][512];     // 2 x 32 reps-rows x 256 B = 16 KB
  __shared__ float colacc[256];      // 1 KB (single wave: plain adds)
  int l = threadIdx.x;               // 0..63
  int kgrp = l >> 4;

  // ---- XCD swizzle (2112 = 8*264, bijective) + block -> (strip it, chunk q) ----
  int b = blockIdx.x;
  int orig = (b & 7) * 264 + (b >> 3);
  int rem = orig, it = 0, ch;
  while (rem >= (ch = (128 - it + 3) >> 2)) { rem -= ch; ++it; }
  int q = rem;
  int rowbase = it * 64;
  int cs0 = rowbase + q * 256;
  int len = NROWS - cs0; if (len > 256) len = 256;
  int ntile = len >> 5;              // 2,4,6,8

#pragma unroll
  for (int i = 0; i < 4; ++i) colacc[l + 64 * i] = 0.f;

  // ---- staging: 32 reps-rows x 256B -> 8KB buffer; linear LDS dest,
  //      4-bit XOR pre-swizzled source (read-side involution) ----
  auto stage = [&](int bufi, int colbase) {
#pragma unroll
    for (int i = 0; i < 8; ++i) {
      int lr = i * 4 + (l >> 4);     // local row 0..31
      int kb = ((l & 15) * 16) ^ ((lr & 15) << 4);
      gload_lds16((const char*)reps_ + (size_t)(colbase + lr) * 256 + kb,
                  (void*)&smem[bufi][i * 64]);
    }
  };
  stage(0, cs0);

  // ---- A fragments: 64-row strip; lane holds row rowbase+fr*16+(l&15) ----
  i32x4 a[4][4];
  {
    const uint4* r4 = (const uint4*)reps_;
    int arow = rowbase + (l & 15);
#pragma unroll
    for (int fr = 0; fr < 4; ++fr)
#pragma unroll
      for (int kk = 0; kk < 4; ++kk)
        a[fr][kk] = __builtin_bit_cast(i32x4,
            r4[(size_t)(arow + fr * 16) * 16 + kk * 4 + kgrp]);
  }

  float rowsum[4][4];
#pragma unroll
  for (int fr = 0; fr < 4; ++fr)
#pragma unroll
    for (int r = 0; r < 4; ++r) rowsum[fr][r] = 0.f;

  int r0 = rowbase + kgrp * 4;
  int buf = 0;
  const int kmad = KMAD;             // SGPR
  const int cbits = CBITS;           // VGPR (2nd const; 1-SGPR rule)

  for (int t = 0; t < ntile; ++t) {
    if (t + 1 < ntile) {
      stage(buf ^ 1, cs0 + 32 * (t + 1));
      asm volatile("s_waitcnt vmcnt(8)" ::: "memory");
    } else {
      asm volatile("s_waitcnt vmcnt(0)" ::: "memory");
    }
    __builtin_amdgcn_sched_barrier(0);

    const char* bb = (const char*)&smem[0][0] + buf * 8192;
    i32x4 acc[4][2];
    const i32x4 zero = {0, 0, 0, 0};
    __builtin_amdgcn_s_setprio(1);
#pragma unroll
    for (int kk = 0; kk < 4; ++kk) {
      i32x4 bf[2];
#pragma unroll
      for (int fc = 0; fc < 2; ++fc) {
        int lr = (l & 15) + fc * 16;
        bf[fc] = *(const i32x4*)(bb + lr * 256 + ((((kk * 4 + kgrp) ^ (lr & 15))) << 4));
      }
#pragma unroll
      for (int fr = 0; fr < 4; ++fr)
#pragma unroll
        for (int fc = 0; fc < 2; ++fc) {
          if (kk == 0)
            acc[fr][fc] = __builtin_amdgcn_mfma_i32_16x16x64_i8(a[fr][0], bf[fc], zero, 0, 0, 0);
          else
            acc[fr][fc] = __builtin_amdgcn_mfma_i32_16x16x64_i8(a[fr][kk], bf[fc], acc[fr][fc], 0, 0, 0);
        }
    }
    __builtin_amdgcn_s_setprio(0);

    // ---- epilogue: e = bitcast(mad_i24(I, K, C)); rowsum + col partials ----
    int cb = cs0 + 32 * t;
    bool docol = !(q == 0 && t < 2);        // diag 64-col window: rowsum only
    bool dopos = (q == 16) && (t < 2);
    float cp0 = 0.f, cp1 = 0.f;
#pragma unroll
    for (int fr = 0; fr < 4; ++fr)
#pragma unroll
      for (int fc = 0; fc < 2; ++fc)
#pragma unroll
        for (int r = 0; r < 4; ++r) {
          int I = acc[fr][fc][r];
          int ib;
          asm("v_mad_i32_i24 %0, %1, %2, %3"
              : "=v"(ib) : "v"(I), "s"(kmad), "v"(cbits));
          float e = __builtin_bit_cast(float, ib);
          if (dopos) {
            int rg = r0 + fr * 16 + r;
            int cg = cb + (l & 15) + fc * 16;
            if (cg == rg + BROWS) pos[rg] = (float)I * FSC;
          }
          rowsum[fr][r] += e;
          if (fc == 0) cp0 += e; else cp1 += e;
        }
    if (docol) {
      cp0 += __shfl_xor(cp0, 16, 64); cp0 += __shfl_xor(cp0, 32, 64);
      cp1 += __shfl_xor(cp1, 16, 64); cp1 += __shfl_xor(cp1, 32, 64);
      if (l < 16) {
        int off = (cb - cs0) + l;
        colacc[off] += cp0;
        colacc[off + 16] += cp1;
      }
    }
    buf ^= 1;
  }

  // ---- row sums: reduce 16 col-lanes; 4 lanes issue global atomics ----
#pragma unroll
  for (int fr = 0; fr < 4; ++fr)
#pragma unroll
    for (int r = 0; r < 4; ++r) {
      float v = rowsum[fr][r];
      v += __shfl_xor(v, 1, 64);
      v += __shfl_xor(v, 2, 64);
      v += __shfl_xor(v, 4, 64);
      v += __shfl_xor(v, 8, 64);
      if ((l & 15) == 0) atomicAdd(&denom[r0 + fr * 16 + r], v);
    }

  // ---- col sums: flush colacc, one atomic per nonzero column ----
#pragma unroll
  for (int i = 0; i < 4; ++i) {
    int off = l + 64 * i;
    float v = colacc[off];
    if (v != 0.f) atomicAdd(&denom[cs0 + off], v);
  }
}

// Kernel F: subtract the (bit-identical) diagonal term, then
// + (1/N) * sum_i (log(denom_i) - pos_{i mod B} * ln2)
__global__ __launch_bounds__(256) void kfin(const float* __restrict__ denom,
                                            const float* __restrict__ pos,
                                            const int* __restrict__ qss,
                                            float* __restrict__ out) {
  int i = blockIdx.x * 256 + threadIdx.x;
  int ib = qss[i] * KMAD + CBITS;           // same int formula as ksim's mad_i24
  float diag_e = __builtin_bit_cast(float, ib);
  float v = (logf(denom[i] - diag_e) - pos[i & 4095] * LN2) * (1.0f / 8192.0f);
#pragma unroll
  for (int m = 1; m < 64; m <<= 1) v += __shfl_xor(v, m, 64);
  __shared__ float part[4];
  if ((threadIdx.x & 63) == 0) part[threadIdx.x >> 6] = v;
  __syncthreads();
  if (threadIdx.x == 0)
    atomicAdd(out, part[0] + part[1] + part[2] + part[3]);
}

extern "C" void kernel_launch(void* const* d_in, const int* in_sizes, int n_in,
                              void* d_out, int out_size, void* d_ws, size_t ws_size,
                              hipStream_t stream) {
  (void)in_sizes; (void)n_in; (void)out_size; (void)ws_size;
  const float* zi = (const float*)d_in[0];
  const float* zj = (const float*)d_in[1];
  float* out = (float*)d_out;
  char* ws = (char*)d_ws;
  int* reps    = (int*)ws;                                    // 2 MB (i8 packed)
  float* denom = (float*)(ws + 2097152);                      // 32 KB
  float* pos   = (float*)(ws + 2097152 + 32768);              // 16 KB
  int* qss     = (int*)(ws + 2097152 + 32768 + 16384);        // 32 KB

  knorm<<<2048, 256, 0, stream>>>(zi, zj, reps, qss, denom, out);
  ksim<<<NBLK, 64, 0, stream>>>(reps, denom, pos);
  kfin<<<32, 256, 0, stream>>>(denom, pos, qss, out);
}